// Round 5
// baseline (159.945 us; speedup 1.0000x reference)
//
#include <hip/hip_runtime.h>
#include <stdint.h>

// ---------------------------------------------------------------------------
// Fused attention: out = dropout(softmax(0.5 * x1 @ x2^T), p=0.2, jax key 42) @ x2
// B=8, M=N=2048, D=128, fp32 in/out. bf16 MFMA (16x16x32), bitwise JAX threefry.
//
// R5 = R4 + (1) threefry rotates forced to v_alignbit_b32, (2) VGPR prefetch
// double-buffer for the x2 staging loads (tile t+1 loads issue during tile t
// compute; ds_write consumes ready registers -> no global latency in the
// per-tile critical path). Structure otherwise identical to R4:
// S^T orientation, TM=32 x TN=32 wave-private tiles, no main-loop barriers,
// fixed-max softmax (exp2(s - 40)), Vt2 plane layout, 2 blocks/CU.
// ---------------------------------------------------------------------------

typedef __bf16 bf16x8 __attribute__((ext_vector_type(8)));
typedef float f32x4 __attribute__((ext_vector_type(4)));

union FragAB {
  bf16x8 v;
  uint32_t u[4];
};

// rotl via alignbit: alignbit(x,x,s) = rotr(x,s) => rotl(x,r) = alignbit(x,x,32-r)
#define ROTL(x, r) __builtin_amdgcn_alignbit((x), (x), 32u - (r))

// JAX threefry2x32 with key (0, 42)
__device__ __forceinline__ void threefry2x32_k42(uint32_t in0, uint32_t in1,
                                                 uint32_t& o0, uint32_t& o1) {
  const uint32_t ks0 = 0u;
  const uint32_t ks1 = 42u;
  const uint32_t ks2 = 0x1BD11BDAu ^ 0u ^ 42u;
  uint32_t x0 = in0 + ks0;
  uint32_t x1 = in1 + ks1;
#define TFR(r) { x0 += x1; x1 = ROTL(x1, r); x1 ^= x0; }
  TFR(13u) TFR(15u) TFR(26u) TFR(6u)
  x0 += ks1; x1 += ks2 + 1u;
  TFR(17u) TFR(29u) TFR(16u) TFR(24u)
  x0 += ks2; x1 += ks0 + 2u;
  TFR(13u) TFR(15u) TFR(26u) TFR(6u)
  x0 += ks0; x1 += ks1 + 3u;
  TFR(17u) TFR(29u) TFR(16u) TFR(24u)
  x0 += ks1; x1 += ks2 + 4u;
  TFR(13u) TFR(15u) TFR(26u) TFR(6u)
  x0 += ks2; x1 += ks0 + 5u;
#undef TFR
  o0 = x0; o1 = x1;
}

__device__ __forceinline__ uint32_t pack_bf16(float a, float b) {
  __bf16 ba = (__bf16)a;   // RTNE
  __bf16 bb = (__bf16)b;
  uint32_t ua = (uint32_t)__builtin_bit_cast(uint16_t, ba);
  uint32_t ub = (uint32_t)__builtin_bit_cast(uint16_t, bb);
  return ua | (ub << 16);
}

// keep iff uniform < 0.8f  <=>  bits < 6710887<<9
#define KEEP_LT 3435974144u
#define MBIAS 40.0f   // fixed softmax bias (log2 domain); scores max ~16 << 40

__launch_bounds__(256, 2)
__global__ void attn_kernel(const float* __restrict__ x1,
                            const float* __restrict__ x2,
                            float* __restrict__ out) {
  // Per-wave region: Kt 32x68w (2176) | Vt2 64x36w (2304) | Pbuf 16x20w (320)
  // = 4800 words = 19200 B; x4 waves = 76800 B total -> 2 blocks/CU.
  __shared__ __attribute__((aligned(16))) uint32_t SMEM[4][4800];

  const int tid = threadIdx.x;
  const int wv = __builtin_amdgcn_readfirstlane(tid >> 6);
  const int lane = tid & 63;
  const int l15 = lane & 15;
  const int g = lane >> 4;
  const int b = blockIdx.y;
  const int m0 = blockIdx.x * 32;

  uint32_t* KtW = &SMEM[wv][0];     // K-tile row-major: row n (32), 68 words
  uint32_t* VtW = &SMEM[wv][2176];  // V^T planes: pair P -> row (P&1)*32+(P>>1), 36 w
  uint32_t* PbW = &SMEM[wv][4480];  // P buffer: row m (16), 20 words

  // ---- Q fragments (B-operand: l15 -> m), scaled by 0.5*log2(e) ----
  const float QSCALE = 0.5f * 1.44269504088896340736f;
  FragAB qf[2][4];
  #pragma unroll
  for (int s = 0; s < 2; ++s) {
    const float* qp_base = x1 + ((size_t)b * 2048 + m0 + s * 16 + l15) * 128;
    #pragma unroll
    for (int c = 0; c < 4; ++c) {
      const float* qp = qp_base + c * 32 + g * 8;
      float4 f0 = *(const float4*)(qp);
      float4 f1 = *(const float4*)(qp + 4);
      qf[s][c].u[0] = pack_bf16(f0.x * QSCALE, f0.y * QSCALE);
      qf[s][c].u[1] = pack_bf16(f0.z * QSCALE, f0.w * QSCALE);
      qf[s][c].u[2] = pack_bf16(f1.x * QSCALE, f1.y * QSCALE);
      qf[s][c].u[3] = pack_bf16(f1.z * QSCALE, f1.w * QSCALE);
    }
  }

  f32x4 o[2][8];
  #pragma unroll
  for (int s = 0; s < 2; ++s)
    #pragma unroll
    for (int dt = 0; dt < 8; ++dt) o[s][dt] = (f32x4){0.f, 0.f, 0.f, 0.f};
  float lsum[2] = {0.f, 0.f};

  uint32_t rb[2];
  #pragma unroll
  for (int s = 0; s < 2; ++s)
    rb[s] = (uint32_t)b * 4194304u +
            (uint32_t)(m0 + s * 16 + l15) * 2048u + (uint32_t)(wv * 512);

  const float4* x2b4 = (const float4*)(x2 + (size_t)b * 2048 * 128);
  const uint32_t permsel = (l15 & 1) ? 0x07060302u : 0x05040100u;

  const int nrow = lane >> 5;        // staging row parity
  const int dq = lane & 31;          // staging d-quad
  const float4* x2stage = x2b4 + (size_t)dq;   // + (n0g + n)*32

  // ---- prefetch tile 0 into registers ----
  float4 pf[16];
  {
    const int n0g = wv * 512;
    #pragma unroll
    for (int i = 0; i < 16; ++i)
      pf[i] = x2stage[(size_t)(n0g + 2 * i + nrow) * 32];
  }

  for (int tile = 0; tile < 16; ++tile) {
    // ---- stage prefetched tile into wave-private Kt (row-major) + Vt2 (planes) ----
    #pragma unroll
    for (int i = 0; i < 16; ++i) {
      int n = 2 * i + nrow;
      uint32_t p0 = pack_bf16(pf[i].x, pf[i].y);
      uint32_t p1 = pack_bf16(pf[i].z, pf[i].w);
      *(uint2*)&KtW[n * 68 + 2 * dq] = make_uint2(p0, p1);
      VtW[dq * 36 + n] = p0;          // pair P=2dq   -> plane row dq
      VtW[(dq + 32) * 36 + n] = p1;   // pair P=2dq+1 -> plane row 32+dq
    }
    // ---- issue next tile's loads now; they complete during this tile's compute ----
    if (tile < 15) {
      const int n0g = wv * 512 + (tile + 1) * 32;
      #pragma unroll
      for (int i = 0; i < 16; ++i)
        pf[i] = x2stage[(size_t)(n0g + 2 * i + nrow) * 32];
    }
    asm volatile("s_waitcnt lgkmcnt(0)" ::: "memory");  // in-order DS per wave

    // ---- S^T = K Q^T : C/D row = n (4g+r), col = m (l15). K-frags shared. ----
    f32x4 sa[2][2];
    #pragma unroll
    for (int s = 0; s < 2; ++s)
      #pragma unroll
      for (int t = 0; t < 2; ++t) sa[s][t] = (f32x4){0.f, 0.f, 0.f, 0.f};
    #pragma unroll
    for (int c = 0; c < 4; ++c) {
      FragAB k0, k1;
      uint4 a0 = *(const uint4*)&KtW[l15 * 68 + c * 16 + 4 * g];
      uint4 a1 = *(const uint4*)&KtW[(16 + l15) * 68 + c * 16 + 4 * g];
      k0.u[0] = a0.x; k0.u[1] = a0.y; k0.u[2] = a0.z; k0.u[3] = a0.w;
      k1.u[0] = a1.x; k1.u[1] = a1.y; k1.u[2] = a1.z; k1.u[3] = a1.w;
      sa[0][0] = __builtin_amdgcn_mfma_f32_16x16x32_bf16(k0.v, qf[0][c].v, sa[0][0], 0, 0, 0);
      sa[0][1] = __builtin_amdgcn_mfma_f32_16x16x32_bf16(k1.v, qf[0][c].v, sa[0][1], 0, 0, 0);
      sa[1][0] = __builtin_amdgcn_mfma_f32_16x16x32_bf16(k0.v, qf[1][c].v, sa[1][0], 0, 0, 0);
      sa[1][1] = __builtin_amdgcn_mfma_f32_16x16x32_bf16(k1.v, qf[1][c].v, sa[1][1], 0, 0, 0);
    }

    // ---- fixed-max softmax + bitwise dropout + P -> Pbuf -> A-frags ----
    FragAB pa[2];
    #pragma unroll
    for (int s = 0; s < 2; ++s) {
      #pragma unroll
      for (int t = 0; t < 2; ++t) {
        float p0 = __builtin_amdgcn_exp2f(sa[s][t][0] - MBIAS);
        float p1 = __builtin_amdgcn_exp2f(sa[s][t][1] - MBIAS);
        float p2 = __builtin_amdgcn_exp2f(sa[s][t][2] - MBIAS);
        float p3 = __builtin_amdgcn_exp2f(sa[s][t][3] - MBIAS);
        lsum[s] += (p0 + p1) + (p2 + p3);   // denominator uses UNMASKED probs
        uint32_t ib = rb[s] + (uint32_t)(tile * 32 + t * 16 + 4 * g);
        uint32_t h0, h1, bits;
        threefry2x32_k42(0u, ib + 0u, h0, h1); bits = h0 ^ h1;
        float q0 = (bits < KEEP_LT) ? p0 : 0.0f;
        threefry2x32_k42(0u, ib + 1u, h0, h1); bits = h0 ^ h1;
        float q1 = (bits < KEEP_LT) ? p1 : 0.0f;
        threefry2x32_k42(0u, ib + 2u, h0, h1); bits = h0 ^ h1;
        float q2 = (bits < KEEP_LT) ? p2 : 0.0f;
        threefry2x32_k42(0u, ib + 3u, h0, h1); bits = h0 ^ h1;
        float q3 = (bits < KEEP_LT) ? p3 : 0.0f;
        *(uint2*)&PbW[l15 * 20 + t * 8 + 2 * g] =
            make_uint2(pack_bf16(q0, q1), pack_bf16(q2, q3));
      }
      asm volatile("s_waitcnt lgkmcnt(0)" ::: "memory");
      uint4 pu = *(const uint4*)&PbW[l15 * 20 + 4 * g];   // A-frag: m=l15, k=8g+j
      pa[s].u[0] = pu.x; pa[s].u[1] = pu.y; pa[s].u[2] = pu.z; pa[s].u[3] = pu.w;
    }

    // ---- O += P V : V-frags (shared across slabs) from Vt2 planes via v_perm ----
    #pragma unroll
    for (int dt = 0; dt < 8; ++dt) {
      int rowp = ((l15 >> 1) & 1) * 32 + 4 * dt + (l15 >> 2);
      const uint32_t* vr = &VtW[rowp * 36 + 8 * g];
      uint4 U0 = *(const uint4*)vr;
      uint4 U1 = *(const uint4*)(vr + 4);
      FragAB vb;
      vb.u[0] = __builtin_amdgcn_perm(U0.y, U0.x, permsel);
      vb.u[1] = __builtin_amdgcn_perm(U0.w, U0.z, permsel);
      vb.u[2] = __builtin_amdgcn_perm(U1.y, U1.x, permsel);
      vb.u[3] = __builtin_amdgcn_perm(U1.w, U1.z, permsel);
      o[0][dt] = __builtin_amdgcn_mfma_f32_16x16x32_bf16(pa[0].v, vb.v, o[0][dt], 0, 0, 0);
      o[1][dt] = __builtin_amdgcn_mfma_f32_16x16x32_bf16(pa[1].v, vb.v, o[1][dt], 0, 0, 0);
    }
  }

  // ---- epilogue: plain-sum merge of 4 N-quarters (no max/alpha needed) ----
  __syncthreads();   // all waves done with their private regions
  float* EP = (float*)&SMEM[0][0];
  // O partials: [(wv*2+s)*8+dt][r] x lane (stride-1, conflict-free). 16384 f.
  // L partials: 16384 + (s*16+col)*16 + (wv*4+g). 512 f. Total 16896 <= 19200.
  #pragma unroll
  for (int s = 0; s < 2; ++s) {
    #pragma unroll
    for (int dt = 0; dt < 8; ++dt)
      #pragma unroll
      for (int r = 0; r < 4; ++r)
        EP[(((wv * 2 + s) * 8 + dt) * 4 + r) * 64 + lane] = o[s][dt][r];
    EP[16384 + (s * 16 + l15) * 16 + wv * 4 + g] = lsum[s];
  }
  __syncthreads();
  const int s = wv >> 1;   // this wave's output slab (items 4wv..4wv+3)
  float scale[4];
  #pragma unroll
  for (int r = 0; r < 4; ++r) {
    const float4* lp = (const float4*)&EP[16384 + (s * 16 + 4 * g + r) * 16];
    float4 A = lp[0], B4 = lp[1], C4 = lp[2], D4 = lp[3];
    float L = ((A.x + A.y) + (A.z + A.w)) + ((B4.x + B4.y) + (B4.z + B4.w)) +
              ((C4.x + C4.y) + (C4.z + C4.w)) + ((D4.x + D4.y) + (D4.z + D4.w));
    scale[r] = 1.0f / (L * 0.8f);
  }
  #pragma unroll
  for (int it = 0; it < 4; ++it) {
    int dt = (wv * 4 + it) & 7;
    #pragma unroll
    for (int r = 0; r < 4; ++r) {
      int base = ((s * 8 + dt) * 4 + r) * 64 + lane;
      float tot = EP[base] + EP[base + 4096] + EP[base + 8192] + EP[base + 12288];
      out[((size_t)b * 2048 + m0 + s * 16 + 4 * g + r) * 128 + dt * 16 + l15] =
          tot * scale[r];
    }
  }
}

extern "C" void kernel_launch(void* const* d_in, const int* in_sizes, int n_in,
                              void* d_out, int out_size, void* d_ws, size_t ws_size,
                              hipStream_t stream) {
  const float* x1 = (const float*)d_in[0];
  const float* x2 = (const float*)d_in[1];
  float* out = (float*)d_out;
  dim3 grid(64, 8, 1);   // (m-tile of 32 rows, batch)
  dim3 block(256, 1, 1); // 4 independent waves, each owns a 512-col N-quarter
  attn_kernel<<<grid, block, 0, stream>>>(x1, x2, out);
}